// Round 8
// baseline (507.868 us; speedup 1.0000x reference)
//
#include <hip/hip_runtime.h>

// Problem constants
#define NB    32
#define CDIM  256
#define HWSZ  4096                 // 64*64
#define NPOS  (NB*HWSZ)            // 131072
#define KCODES 1024
#define QELEMS ((size_t)NB*CDIM*HWSZ)   // 33554432
#define IDX_OFF QELEMS
#define DIFF_OFF (QELEMS + NPOS)
#define EBYTES (64*16384)          // 1 MB: [ch(2)][tile(32)][16KB] pre-arranged fp16 codebook
#define E2F_OFF (EBYTES/4)         // float offset 262144 for e2 table (4 KB)
#define TAB_BYTE (EBYTES + 4096)   // byte offset of u64 argmin table (1 MB)

// LDS map (stage1) — total 67712 B -> 2 blocks/CU
#define BOFF  32768                // B: 2 x 16 KB ring
#define X2P   65536                // x2 partials [8][32] f32 = 1 KB
#define X2T   66560                // x2 totals [32] f32
#define MVOFF 66688                // merge vals [4][32] f32
#define MIOFF 67200                // merge idx  [4][32] i32
#define LDSSZ 67712

typedef _Float16       f16x8  __attribute__((ext_vector_type(8)));
typedef float          f32x16 __attribute__((ext_vector_type(16)));
typedef unsigned short u16x8  __attribute__((ext_vector_type(8)));

static __device__ inline unsigned short f2h(float f) {
    _Float16 h = (_Float16)f;
    return __builtin_bit_cast(unsigned short, h);
}

// ---------------------------------------------------------------------------
// prep_embed: pre-arranged fp16 codebook in d_out scratch, matching stage1's
// B LDS tiles exactly (linear global_load_lds copy).
// Per code-half ch (512 codes): 32 tiles of 16 KB; tile t<16 = eh k-chunk t,
// t>=16 = (el*64) k-chunk t-16. Within tile: byte = hi*8192 + code*16 + sub*2.
// Also e2[k], init u64 argmin table to ~0, zero diff.
// ---------------------------------------------------------------------------
__global__ __launch_bounds__(64) void vq_prep_embed(const float* __restrict__ embed,
                                                    float* __restrict__ out) {
    const int k = blockIdx.x;
    const int lane = threadIdx.x;
    const float4 v = *reinterpret_cast<const float4*>(embed + (size_t)k * CDIM + lane * 4);

    unsigned char* __restrict__ ebuf = (unsigned char*)out;

    _Float16 h0 = (_Float16)v.x, h1 = (_Float16)v.y, h2 = (_Float16)v.z, h3 = (_Float16)v.w;
    ushort4 hv = { __builtin_bit_cast(unsigned short, h0), __builtin_bit_cast(unsigned short, h1),
                   __builtin_bit_cast(unsigned short, h2), __builtin_bit_cast(unsigned short, h3) };
    ushort4 lv = { f2h((v.x - (float)h0) * 64.0f), f2h((v.y - (float)h1) * 64.0f),
                   f2h((v.z - (float)h2) * 64.0f), f2h((v.w - (float)h3) * 64.0f) };

    const int ch = k >> 9;
    const int ck = k & 511;
    const int c0 = lane * 4;
    const int tile = c0 >> 4;            // k-chunk 0..15
    const int hi   = (c0 >> 3) & 1;
    const int sub  = c0 & 7;
    const size_t base = (size_t)(ch * 32 + tile) * 16384 + hi * 8192 + (size_t)ck * 16 + sub * 2;
    *reinterpret_cast<ushort4*>(ebuf + base)              = hv;   // eh   (tiles 0-15)
    *reinterpret_cast<ushort4*>(ebuf + base + 16 * 16384) = lv;   // el*64 (tiles 16-31)

    float s = v.x * v.x + v.y * v.y + v.z * v.z + v.w * v.w;
    #pragma unroll
    for (int m = 1; m < 64; m <<= 1) s += __shfl_xor(s, m, 64);
    if (lane == 0) out[E2F_OFF + k] = s;

    // argmin table init (1024 blocks x 64 lanes x 2 = 131072 entries)
    unsigned long long* tab = (unsigned long long*)((unsigned char*)out + TAB_BYTE);
    const int i0 = (k * 64 + lane) * 2;
    tab[i0]     = ~0ULL;
    tab[i0 + 1] = ~0ULL;
    if (k == 0 && lane == 0) out[DIFF_OFF] = 0.0f;
}

// ---------------------------------------------------------------------------
// stage1: fused fp16-split 32x32x16 MFMA distance + per-block argmin.
// Block: 256 thr = 4 waves, 32 positions x 512 codes (code-half = bid&1).
// Two such blocks co-resident per CU (LDS 66 KB) -> independent 4-wave
// barrier groups overlap each other's stalls.
// dot = xh*eh + (xl*64)*(eh/64) + (xh/64)*(el*64); acc[4] f32x16.
// Ring-2 B (16 KB tiles), counted s_waitcnt vmcnt(4) (never drain to 0).
// Result via packed-u64 atomicMin( dist_bits<<32 | code ).
// ---------------------------------------------------------------------------
__global__ __launch_bounds__(256, 2) void vq_stage1(const float* __restrict__ x,
                                                    float* __restrict__ out) {
    __shared__ __align__(16) unsigned char lds[LDSSZ];

    const unsigned char* __restrict__ ebuf = (const unsigned char*)out;
    const float* __restrict__ e2buf = out + E2F_OFF;
    unsigned long long* __restrict__ tab =
        (unsigned long long*)((unsigned char*)out + TAB_BYTE);

    const int t     = threadIdx.x;
    const int lane  = t & 63;
    const int col32 = lane & 31;
    const int hi    = lane >> 5;
    const int widx  = t >> 6;          // wave 0..3 : 128-code group

    const int ch   = blockIdx.x & 1;          // code half (0..1)
    const int pb   = blockIdx.x >> 1;         // position block (0..4095)
    const int pos0 = pb * 32;
    const int n    = pos0 >> 12;
    const int hw0  = pos0 & 4095;
    const float* __restrict__ xbase = x + (size_t)n * (CDIM * HWSZ) + hw0;

    // ---- A staging: x fp32 -> fp16 (xh | xl*64), [32 kchunks][2 kh][32 pos][16B]
    {
        const int i = t & 31;          // position (coalesced)
        const int g = t >> 5;          // channel group 0..7 (32 ch each)
        float x2p = 0.f;
        #pragma unroll
        for (int j = 0; j < 4; ++j) {
            const int c0 = g * 32 + j * 8;
            u16x8 hv, lv;
            #pragma unroll
            for (int q = 0; q < 8; ++q) {
                float vv = xbase[(size_t)(c0 + q) * HWSZ + i];
                x2p = fmaf(vv, vv, x2p);
                _Float16 hh = (_Float16)vv;
                hv[q] = __builtin_bit_cast(unsigned short, hh);
                lv[q] = f2h((vv - (float)hh) * 64.0f);
            }
            const int a  = c0 >> 4;
            const int kh = (c0 >> 3) & 1;
            const int byte = a * 1024 + kh * 512 + i * 16;
            *reinterpret_cast<u16x8*>(lds + byte)         = hv;   // xh   (chunks 0-15)
            *reinterpret_cast<u16x8*>(lds + byte + 16384) = lv;   // xl*64 (chunks 16-31)
        }
        ((float*)(lds + X2P))[g * 32 + i] = x2p;
    }

    // ---- async B staging (linear copy). 4 glds per wave per 16 KB tile.
    auto stage = [&](int tile, int buf) {
        const unsigned char* src = ebuf + (size_t)(ch * 32 + tile) * 16384;
        unsigned char* dst = lds + BOFF + buf * 16384;
        #pragma unroll
        for (int ii = 0; ii < 4; ++ii) {
            const int chunk = (widx * 4 + ii) * 1024;
            __builtin_amdgcn_global_load_lds(
                (const __attribute__((address_space(1))) unsigned int*)(src + chunk + lane * 16),
                (__attribute__((address_space(3))) unsigned int*)(dst + chunk),
                16, 0, 0);
        }
    };

    __syncthreads();            // A + x2 partials visible; vmcnt drained
    stage(0, 0);                // tile 0 in flight (4 outstanding/wave)

    // x2 totals (wave 0; consumed only after loop barriers)
    if (t < 32) {
        const float* p = (const float*)(lds + X2P);
        float s = 0.f;
        #pragma unroll
        for (int g = 0; g < 8; ++g) s += p[g * 32 + t];
        ((float*)(lds + X2T))[t] = s;
    }

    f32x16 acc[4];
    #pragma unroll
    for (int cb = 0; cb < 4; ++cb)
        #pragma unroll
        for (int r = 0; r < 16; ++r) acc[cb][r] = 0.f;

    const int aoff = hi * 512 + col32 * 16;
    const int boff = hi * 8192 + (widx * 128 + col32) * 16;   // + cb*512

    // ---- main loop: 32 tiles (16 eh used twice, 16 el); only stage() VMEM inside
    for (int kt = 0; kt < 32; ++kt) {
        stage((kt + 1) & 31, (kt + 1) & 1);                // prefetch next tile

        asm volatile("s_waitcnt vmcnt(4)" ::: "memory");   // own tile-kt loads done
        __builtin_amdgcn_s_barrier();                      // => all waves' done
        __builtin_amdgcn_sched_barrier(0);

        const int a = (kt < 16) ? kt : kt - 16;
        const unsigned char* ab = lds + a * 1024;
        const unsigned char* bb = lds + BOFF + (kt & 1) * 16384;

        f16x8 bv[4];
        #pragma unroll
        for (int cb = 0; cb < 4; ++cb)
            bv[cb] = *reinterpret_cast<const f16x8*>(bb + boff + cb * 512);

        if (kt < 16) {
            // seg0: xh * eh
            f16x8 ah = *reinterpret_cast<const f16x8*>(ab + aoff);
            __builtin_amdgcn_s_setprio(1);
            #pragma unroll
            for (int cb = 0; cb < 4; ++cb)
                acc[cb] = __builtin_amdgcn_mfma_f32_32x32x16_f16(ah, bv[cb], acc[cb], 0, 0, 0);
            __builtin_amdgcn_s_setprio(0);
            // seg2: (xl*64) * (eh/64)
            f16x8 al = *reinterpret_cast<const f16x8*>(ab + 16384 + aoff);
            #pragma unroll
            for (int cb = 0; cb < 4; ++cb) bv[cb] *= (_Float16)0.015625f;
            __builtin_amdgcn_s_setprio(1);
            #pragma unroll
            for (int cb = 0; cb < 4; ++cb)
                acc[cb] = __builtin_amdgcn_mfma_f32_32x32x16_f16(al, bv[cb], acc[cb], 0, 0, 0);
            __builtin_amdgcn_s_setprio(0);
        } else {
            // seg1: (xh/64) * (el*64)
            f16x8 ah = *reinterpret_cast<const f16x8*>(ab + aoff);
            ah *= (_Float16)0.015625f;
            __builtin_amdgcn_s_setprio(1);
            #pragma unroll
            for (int cb = 0; cb < 4; ++cb)
                acc[cb] = __builtin_amdgcn_mfma_f32_32x32x16_f16(ah, bv[cb], acc[cb], 0, 0, 0);
            __builtin_amdgcn_s_setprio(0);
        }

        __builtin_amdgcn_s_barrier();   // reads of this buf done before reuse
    }

    // ---- epilogue: scores, in-wave argmin, cross-wave merge, atomicMin
    const float* x2t = (const float*)(lds + X2T);
    float e2v[4];
    #pragma unroll
    for (int cb = 0; cb < 4; ++cb)
        e2v[cb] = e2buf[ch * 512 + widx * 128 + cb * 32 + col32];

    float* mv = (float*)(lds + MVOFF);
    int*   mi = (int*)(lds + MIOFF);

    #pragma unroll
    for (int reg = 0; reg < 16; ++reg) {
        const int pos = (reg & 3) + 8 * (reg >> 2) + 4 * hi;
        const float x2 = x2t[pos];
        float bv_ = 3.4e38f;
        int   bi_ = 0;
        #pragma unroll
        for (int cb = 0; cb < 4; ++cb) {
            const int code = ch * 512 + widx * 128 + cb * 32 + col32;
            const float s = fmaxf((x2 - 2.0f * acc[cb][reg]) + e2v[cb], 0.0f);
            if (s < bv_) { bv_ = s; bi_ = code; }
        }
        // shuffle-merge over the 32 code columns (stays within 32-lane half)
        #pragma unroll
        for (int m = 1; m < 32; m <<= 1) {
            float ov = __shfl_xor(bv_, m, 64);
            int   oi = __shfl_xor(bi_, m, 64);
            if (ov < bv_ || (ov == bv_ && oi < bi_)) { bv_ = ov; bi_ = oi; }
        }
        if (col32 == 0) {
            mv[widx * 32 + pos] = bv_;
            mi[widx * 32 + pos] = bi_;
        }
    }

    __syncthreads();
    if (t < 32) {
        float bv_ = mv[t];
        int   bi_ = mi[t];
        #pragma unroll
        for (int w = 1; w < 4; ++w) {
            const float ov = mv[w * 32 + t];
            const int   oi = mi[w * 32 + t];
            if (ov < bv_ || (ov == bv_ && oi < bi_)) { bv_ = ov; bi_ = oi; }
        }
        const unsigned long long pack =
            ((unsigned long long)__float_as_uint(bv_) << 32) | (unsigned)bi_;
        atomicMin(&tab[pos0 + t], pack);
    }
}

// ---------------------------------------------------------------------------
// extract: unpack argmin table -> idx floats; reduce diff = sum(min dist)/N.
// Must run after stage1, before gather.
// ---------------------------------------------------------------------------
__global__ __launch_bounds__(256) void vq_extract(float* __restrict__ out) {
    const unsigned long long* __restrict__ tab =
        (const unsigned long long*)((unsigned char*)out + TAB_BYTE);
    const int p = blockIdx.x * 256 + threadIdx.x;
    const unsigned long long v = tab[p];
    out[IDX_OFF + p] = (float)(unsigned)(v & 0xFFFFFFFFu);
    float d = __uint_as_float((unsigned)(v >> 32));

    #pragma unroll
    for (int m = 1; m < 64; m <<= 1) d += __shfl_xor(d, m, 64);
    __shared__ float red[4];
    const int lane = threadIdx.x & 63;
    const int w = threadIdx.x >> 6;
    if (lane == 0) red[w] = d;
    __syncthreads();
    if (threadIdx.x == 0) {
        float s = red[0] + red[1] + red[2] + red[3];
        atomicAdd(out + DIFF_OFF, s * (1.0f / 33554432.0f));
    }
}

// ---------------------------------------------------------------------------
// gather: quantize = embed[idx] (NCHW).
// ---------------------------------------------------------------------------
__global__ __launch_bounds__(256) void vq_gather_kernel(const float* __restrict__ embed,
                                                        float* __restrict__ out) {
    const int tid = threadIdx.x;
    const int p = blockIdx.x * 256 + tid;
    const int n = p >> 12;
    const int hw = p & 4095;
    const int idx = (int)out[IDX_OFF + p];
    const float4* __restrict__ erow4 = reinterpret_cast<const float4*>(embed + (size_t)idx * CDIM);
    float* __restrict__ op = out + (size_t)n * (CDIM * HWSZ) + hw;

    #pragma unroll 8
    for (int c4 = 0; c4 < 64; ++c4) {
        const float4 e = erow4[c4];
        op[(size_t)(c4 * 4 + 0) * HWSZ] = e.x;
        op[(size_t)(c4 * 4 + 1) * HWSZ] = e.y;
        op[(size_t)(c4 * 4 + 2) * HWSZ] = e.z;
        op[(size_t)(c4 * 4 + 3) * HWSZ] = e.w;
    }
}

extern "C" void kernel_launch(void* const* d_in, const int* in_sizes, int n_in,
                              void* d_out, int out_size, void* d_ws, size_t ws_size,
                              hipStream_t stream) {
    const float* x = (const float*)d_in[0];
    const float* embed = (const float*)d_in[1];
    float* out = (float*)d_out;

    vq_prep_embed<<<KCODES, 64, 0, stream>>>(embed, out);
    vq_stage1<<<(NPOS / 32) * 2, 256, 0, stream>>>(x, out);
    vq_extract<<<NPOS / 256, 256, 0, stream>>>(out);
    vq_gather_kernel<<<NPOS / 256, 256, 0, stream>>>(embed, out);
}

// Round 9
// 413.312 us; speedup vs baseline: 1.2288x; 1.2288x over previous
//
#include <hip/hip_runtime.h>

// Problem constants
#define NB    32
#define CDIM  256
#define HWSZ  4096                 // 64*64
#define NPOS  (NB*HWSZ)            // 131072
#define KCODES 1024
#define QELEMS ((size_t)NB*CDIM*HWSZ)   // 33554432
#define IDX_OFF QELEMS
#define DIFF_OFF (QELEMS + NPOS)
#define EBYTES (32*32768)          // 1 MB: [region 0..31][code 0..1023][32B]
#define E2F_OFF (EBYTES/4)         // float offset 262144 for e2 table

// LDS map (stage1): A 64 KB + reduction scratch
#define X2P   65536                // x2 partials [8][64] f32 = 2 KB
#define X2T   67584                // x2 totals  [64] f32
#define MVOFF 67840                // merge vals [8][64] f32 = 2 KB
#define MIOFF 69888                // merge idx  [8][64] i32 = 2 KB
#define LDSSZ 71936

typedef _Float16       f16x8  __attribute__((ext_vector_type(8)));
typedef float          f32x16 __attribute__((ext_vector_type(16)));
typedef unsigned short u16x8  __attribute__((ext_vector_type(8)));

static __device__ inline unsigned short f2h(float f) {
    _Float16 h = (_Float16)f;
    return __builtin_bit_cast(unsigned short, h);
}

// ---------------------------------------------------------------------------
// prep_embed: codebook rearranged for per-lane register loads in stage1.
// Region r in [0,16): eh k-chunk r.  Region 16+r: (el*64) k-chunk r.
// Within region: byte = code*32 + hi*16 + sub*2   (hi=(c>>3)&1, sub=c&7).
// Also e2[k] (fp32); zero diff accumulator.
// ---------------------------------------------------------------------------
__global__ __launch_bounds__(64) void vq_prep_embed(const float* __restrict__ embed,
                                                    float* __restrict__ out) {
    const int k = blockIdx.x;
    const int lane = threadIdx.x;
    const float4 v = *reinterpret_cast<const float4*>(embed + (size_t)k * CDIM + lane * 4);

    unsigned char* __restrict__ ebuf = (unsigned char*)out;

    _Float16 h0 = (_Float16)v.x, h1 = (_Float16)v.y, h2 = (_Float16)v.z, h3 = (_Float16)v.w;
    ushort4 hv = { __builtin_bit_cast(unsigned short, h0), __builtin_bit_cast(unsigned short, h1),
                   __builtin_bit_cast(unsigned short, h2), __builtin_bit_cast(unsigned short, h3) };
    ushort4 lv = { f2h((v.x - (float)h0) * 64.0f), f2h((v.y - (float)h1) * 64.0f),
                   f2h((v.z - (float)h2) * 64.0f), f2h((v.w - (float)h3) * 64.0f) };

    const int c0  = lane * 4;
    const int r   = c0 >> 4;             // k-chunk 0..15
    const int hi  = (c0 >> 3) & 1;
    const int sub = c0 & 7;
    const size_t byte = (size_t)r * 32768 + (size_t)k * 32 + hi * 16 + sub * 2;
    *reinterpret_cast<ushort4*>(ebuf + byte)              = hv;   // eh    (regions 0-15)
    *reinterpret_cast<ushort4*>(ebuf + byte + 16 * 32768) = lv;   // el*64 (regions 16-31)

    float s = v.x * v.x + v.y * v.y + v.z * v.z + v.w * v.w;
    #pragma unroll
    for (int m = 1; m < 64; m <<= 1) s += __shfl_xor(s, m, 64);
    if (lane == 0) out[E2F_OFF + k] = s;
    if (k == 0 && lane == 0) out[DIFF_OFF] = 0.0f;
}

// ---------------------------------------------------------------------------
// stage1: fused fp16-split 32x32x16 MFMA distance + argmin + diff.
// 512 thr = 8 waves; wave w covers all 64 positions x codes [w*128, w*128+128).
// B comes straight from global (L2) into registers: 4 coalesced dwordx4 per
// lane per step, NO LDS staging for B and NO barriers in the K-loop — the
// 8 waves run free, loads pipeline across steps.
// A (shared by all waves) in LDS, read-only after prologue.
// Virtual K=768: seg0 xh*eh | seg1 (xh/64)*(el*64) | seg2 (xl*64)*(eh/64).
// acc[2][4] f32x16 = 128 AGPRs (r5-proven uniform body, no spill).
// ---------------------------------------------------------------------------
__global__ __launch_bounds__(512) void vq_stage1(const float* __restrict__ x,
                                                 float* __restrict__ out) {
    __shared__ __align__(16) unsigned char lds[LDSSZ];

    const unsigned char* __restrict__ ebuf = (const unsigned char*)out;
    const float* __restrict__ e2buf = out + E2F_OFF;
    float* __restrict__ idx_out = out + IDX_OFF;

    const int t     = threadIdx.x;
    const int lane  = t & 63;
    const int col32 = lane & 31;
    const int hi    = lane >> 5;
    const int widx  = t >> 6;          // wave 0..7 : code group of 128

    const int pos0 = blockIdx.x * 64;
    const int n    = pos0 >> 12;
    const int hw0  = pos0 & 4095;
    const float* __restrict__ xbase = x + (size_t)n * (CDIM * HWSZ) + hw0;

    // ---- A staging: x fp32 -> fp16 (xh | xl*64), [16 kc][2 kh][64 pos][16B]
    {
        const int i = t & 63;          // position (coalesced)
        const int g = t >> 6;          // channel group (32 ch)
        float x2p = 0.f;
        #pragma unroll
        for (int j = 0; j < 4; ++j) {
            const int c0 = g * 32 + j * 8;
            u16x8 hv, lv;
            #pragma unroll
            for (int q = 0; q < 8; ++q) {
                float vv = xbase[(size_t)(c0 + q) * HWSZ + i];
                x2p = fmaf(vv, vv, x2p);
                _Float16 hh = (_Float16)vv;
                hv[q] = __builtin_bit_cast(unsigned short, hh);
                lv[q] = f2h((vv - (float)hh) * 64.0f);
            }
            const int kc = c0 >> 4;
            const int kh = (c0 >> 3) & 1;
            const int byte = kc * 2048 + kh * 1024 + i * 16;
            *reinterpret_cast<u16x8*>(lds + byte)         = hv;   // xh
            *reinterpret_cast<u16x8*>(lds + byte + 32768) = lv;   // xl*64
        }
        ((float*)(lds + X2P))[g * 64 + i] = x2p;
    }
    __syncthreads();

    // x2 totals (wave 0), then one more barrier so everyone may read X2T later
    if (t < 64) {
        const float* p = (const float*)(lds + X2P);
        float s = 0.f;
        #pragma unroll
        for (int g = 0; g < 8; ++g) s += p[g * 64 + t];
        ((float*)(lds + X2T))[t] = s;
    }
    __syncthreads();

    f32x16 acc[2][4];
    #pragma unroll
    for (int ra = 0; ra < 2; ++ra)
        #pragma unroll
        for (int cb = 0; cb < 4; ++cb)
            #pragma unroll
            for (int r = 0; r < 16; ++r) acc[ra][cb][r] = 0.f;

    // loop-invariant offsets
    const int aoff = hi * 1024 + col32 * 16;                       // + ra*512
    const unsigned char* __restrict__ bbase =
        ebuf + (size_t)widx * 4096 + (size_t)col32 * 32 + (size_t)hi * 16;  // + cb*1024

    // ---- main loop: 48 uniform steps, NO barriers — waves fully independent
    #pragma unroll 2
    for (int kq = 0; kq < 48; ++kq) {
        const int seg = kq >> 4;                       // 0,1,2 (block-uniform)
        const int r   = (kq < 32) ? kq : (kq - 32);    // B region
        const unsigned char* ab = lds + (kq & 15) * 2048 + ((seg == 2) ? 32768 : 0);
        const unsigned char* bp = bbase + (size_t)r * 32768;

        f16x8 a0 = *reinterpret_cast<const f16x8*>(ab + aoff);
        f16x8 a1 = *reinterpret_cast<const f16x8*>(ab + aoff + 512);
        f16x8 b0 = *reinterpret_cast<const f16x8*>(bp);
        f16x8 b1 = *reinterpret_cast<const f16x8*>(bp + 1024);
        f16x8 b2 = *reinterpret_cast<const f16x8*>(bp + 2048);
        f16x8 b3 = *reinterpret_cast<const f16x8*>(bp + 3072);

        if (seg == 1) {                 // (xh/64) * (el*64)
            a0 *= (_Float16)0.015625f;
            a1 *= (_Float16)0.015625f;
        } else if (seg == 2) {          // (xl*64) * (eh/64)
            b0 *= (_Float16)0.015625f;
            b1 *= (_Float16)0.015625f;
            b2 *= (_Float16)0.015625f;
            b3 *= (_Float16)0.015625f;
        }

        __builtin_amdgcn_s_setprio(1);
        acc[0][0] = __builtin_amdgcn_mfma_f32_32x32x16_f16(a0, b0, acc[0][0], 0, 0, 0);
        acc[0][1] = __builtin_amdgcn_mfma_f32_32x32x16_f16(a0, b1, acc[0][1], 0, 0, 0);
        acc[0][2] = __builtin_amdgcn_mfma_f32_32x32x16_f16(a0, b2, acc[0][2], 0, 0, 0);
        acc[0][3] = __builtin_amdgcn_mfma_f32_32x32x16_f16(a0, b3, acc[0][3], 0, 0, 0);
        acc[1][0] = __builtin_amdgcn_mfma_f32_32x32x16_f16(a1, b0, acc[1][0], 0, 0, 0);
        acc[1][1] = __builtin_amdgcn_mfma_f32_32x32x16_f16(a1, b1, acc[1][1], 0, 0, 0);
        acc[1][2] = __builtin_amdgcn_mfma_f32_32x32x16_f16(a1, b2, acc[1][2], 0, 0, 0);
        acc[1][3] = __builtin_amdgcn_mfma_f32_32x32x16_f16(a1, b3, acc[1][3], 0, 0, 0);
        __builtin_amdgcn_s_setprio(0);
    }

    // ---- epilogue: scores, in-wave argmin, cross-wave merge
    const float* x2t = (const float*)(lds + X2T);
    float e2v[4];
    #pragma unroll
    for (int cb = 0; cb < 4; ++cb)
        e2v[cb] = e2buf[widx * 128 + cb * 32 + col32];

    float* mv = (float*)(lds + MVOFF);
    int*   mi = (int*)(lds + MIOFF);

    #pragma unroll
    for (int ra = 0; ra < 2; ++ra) {
        #pragma unroll
        for (int reg = 0; reg < 16; ++reg) {
            const int pos = ra * 32 + (reg & 3) + 8 * (reg >> 2) + 4 * hi;
            const float x2 = x2t[pos];
            float bv_ = 3.4e38f;
            int   bi_ = 0;
            #pragma unroll
            for (int cb = 0; cb < 4; ++cb) {
                const int code = widx * 128 + cb * 32 + col32;
                const float s = (x2 - 2.0f * acc[ra][cb][reg]) + e2v[cb];
                if (s < bv_) { bv_ = s; bi_ = code; }
            }
            // shuffle-merge over the 32 code columns (stays within 32-lane half)
            #pragma unroll
            for (int m = 1; m < 32; m <<= 1) {
                float ov = __shfl_xor(bv_, m, 64);
                int   oi = __shfl_xor(bi_, m, 64);
                if (ov < bv_ || (ov == bv_ && oi < bi_)) { bv_ = ov; bi_ = oi; }
            }
            if (col32 == 0) {
                mv[widx * 64 + pos] = bv_;
                mi[widx * 64 + pos] = bi_;
            }
        }
    }

    __syncthreads();
    if (t < 64) {
        float bv_ = mv[t];
        int   bi_ = mi[t];
        #pragma unroll
        for (int w = 1; w < 8; ++w) {
            const float ov = mv[w * 64 + t];
            const int   oi = mi[w * 64 + t];
            if (ov < bv_ || (ov == bv_ && oi < bi_)) { bv_ = ov; bi_ = oi; }
        }
        idx_out[pos0 + t] = (float)bi_;
        // diff partial = sum of min distances
        float d = bv_;
        #pragma unroll
        for (int m = 1; m < 64; m <<= 1) d += __shfl_xor(d, m, 64);
        if (t == 0) atomicAdd(out + DIFF_OFF, d * (1.0f / 33554432.0f));
    }
}

// ---------------------------------------------------------------------------
// gather: quantize = embed[idx] (NCHW). Diff already done in stage1.
// ---------------------------------------------------------------------------
__global__ __launch_bounds__(256) void vq_gather_kernel(const float* __restrict__ embed,
                                                        float* __restrict__ out) {
    const int tid = threadIdx.x;
    const int p = blockIdx.x * 256 + tid;
    const int n = p >> 12;
    const int hw = p & 4095;
    const int idx = (int)out[IDX_OFF + p];
    const float4* __restrict__ erow4 = reinterpret_cast<const float4*>(embed + (size_t)idx * CDIM);
    float* __restrict__ op = out + (size_t)n * (CDIM * HWSZ) + hw;

    #pragma unroll 8
    for (int c4 = 0; c4 < 64; ++c4) {
        const float4 e = erow4[c4];
        op[(size_t)(c4 * 4 + 0) * HWSZ] = e.x;
        op[(size_t)(c4 * 4 + 1) * HWSZ] = e.y;
        op[(size_t)(c4 * 4 + 2) * HWSZ] = e.z;
        op[(size_t)(c4 * 4 + 3) * HWSZ] = e.w;
    }
}

extern "C" void kernel_launch(void* const* d_in, const int* in_sizes, int n_in,
                              void* d_out, int out_size, void* d_ws, size_t ws_size,
                              hipStream_t stream) {
    const float* x = (const float*)d_in[0];
    const float* embed = (const float*)d_in[1];
    float* out = (float*)d_out;

    vq_prep_embed<<<KCODES, 64, 0, stream>>>(embed, out);
    vq_stage1<<<NPOS / 64, 512, 0, stream>>>(x, out);
    vq_gather_kernel<<<NPOS / 256, 256, 0, stream>>>(embed, out);
}

// Round 10
// 388.287 us; speedup vs baseline: 1.3080x; 1.0644x over previous
//
#include <hip/hip_runtime.h>

// Problem constants
#define NB    32
#define CDIM  256
#define HWSZ  4096                 // 64*64
#define NPOS  (NB*HWSZ)            // 131072
#define KCODES 1024
#define QELEMS ((size_t)NB*CDIM*HWSZ)   // 33554432
#define IDX_OFF QELEMS
#define DIFF_OFF (QELEMS + NPOS)
// Codebook: 48 regions x 32 KB = 1.5 MB in d_out scratch.
// Region r<16: eh k-chunk r | 16..31: (el*64) chunk r-16 | 32..47: (eh/64) chunk r-32
#define EBYTES (48*32768)
#define E2F_OFF (EBYTES/4)         // float offset 393216 for e2 table

// LDS map (stage1): A 96 KB (xh | xh/64 | xl*64) + scratch
#define X2P   98304                // x2 partials [16][64] f32 = 4 KB
#define X2T   102400               // x2 totals  [64] f32
#define MVOFF 102656               // merge vals [16][64] f32 = 4 KB
#define MIOFF 106752               // merge idx  [16][64] i32 = 4 KB
#define LDSSZ 110848

typedef _Float16       f16x8  __attribute__((ext_vector_type(8)));
typedef float          f32x16 __attribute__((ext_vector_type(16)));
typedef unsigned short u16x8  __attribute__((ext_vector_type(8)));

static __device__ inline unsigned short f2h(float f) {
    _Float16 h = (_Float16)f;
    return __builtin_bit_cast(unsigned short, h);
}

// ---------------------------------------------------------------------------
// prep_embed: codebook rearranged + pre-scaled for stage1 register loads.
// Within region: byte = code*32 + kh*16 + sub*2   (kh=(c>>3)&1, sub=c&7).
// Also e2[k] (fp32); zero diff accumulator.
// ---------------------------------------------------------------------------
__global__ __launch_bounds__(64) void vq_prep_embed(const float* __restrict__ embed,
                                                    float* __restrict__ out) {
    const int k = blockIdx.x;
    const int lane = threadIdx.x;
    const float4 v = *reinterpret_cast<const float4*>(embed + (size_t)k * CDIM + lane * 4);

    unsigned char* __restrict__ ebuf = (unsigned char*)out;

    _Float16 h0 = (_Float16)v.x, h1 = (_Float16)v.y, h2 = (_Float16)v.z, h3 = (_Float16)v.w;
    ushort4 hv = { __builtin_bit_cast(unsigned short, h0), __builtin_bit_cast(unsigned short, h1),
                   __builtin_bit_cast(unsigned short, h2), __builtin_bit_cast(unsigned short, h3) };
    ushort4 lv = { f2h((v.x - (float)h0) * 64.0f), f2h((v.y - (float)h1) * 64.0f),
                   f2h((v.z - (float)h2) * 64.0f), f2h((v.w - (float)h3) * 64.0f) };
    ushort4 hv64 = { f2h((float)h0 * 0.015625f), f2h((float)h1 * 0.015625f),
                     f2h((float)h2 * 0.015625f), f2h((float)h3 * 0.015625f) };

    const int c0  = lane * 4;
    const int kc  = c0 >> 4;             // k-chunk 0..15
    const int kh  = (c0 >> 3) & 1;
    const int sub = c0 & 7;
    const size_t byte = (size_t)kc * 32768 + (size_t)k * 32 + kh * 16 + sub * 2;
    *reinterpret_cast<ushort4*>(ebuf + byte)              = hv;    // eh    (regions 0-15)
    *reinterpret_cast<ushort4*>(ebuf + byte + 16 * 32768) = lv;    // el*64 (regions 16-31)
    *reinterpret_cast<ushort4*>(ebuf + byte + 32 * 32768) = hv64;  // eh/64 (regions 32-47)

    float s = v.x * v.x + v.y * v.y + v.z * v.z + v.w * v.w;
    #pragma unroll
    for (int m = 1; m < 64; m <<= 1) s += __shfl_xor(s, m, 64);
    if (lane == 0) out[E2F_OFF + k] = s;
    if (k == 0 && lane == 0) out[DIFF_OFF] = 0.0f;
}

// ---------------------------------------------------------------------------
// stage1: fused fp16-split 32x32x16 MFMA distance + argmin + diff.
// 1024 thr = 16 waves; wave w covers all 64 positions x codes [w*64, w*64+64).
// acc[2][2] = 64 AGPR; total regs ~103 -> 4 waves/SIMD (16 waves/CU).
// Virtual K = 768 as 48 steps: seg0 xh*eh | seg1 (xh/64)*(el*64) |
// seg2 (xl*64)*(eh/64) — all scales pre-baked, ZERO VALU in loop.
// B direct from L2 to registers, double-buffered (prefetch k+1 before MFMA k);
// A from LDS (read-only after prologue). NO barriers in the 24-iter loop.
// ---------------------------------------------------------------------------
__global__ __launch_bounds__(1024) void vq_stage1(const float* __restrict__ x,
                                                  float* __restrict__ out) {
    __shared__ __align__(16) unsigned char lds[LDSSZ];

    const unsigned char* __restrict__ ebuf = (const unsigned char*)out;
    const float* __restrict__ e2buf = out + E2F_OFF;
    float* __restrict__ idx_out = out + IDX_OFF;

    const int t     = threadIdx.x;
    const int lane  = t & 63;
    const int col32 = lane & 31;
    const int hi    = lane >> 5;
    const int widx  = t >> 6;          // wave 0..15 : code group of 64

    const int pos0 = blockIdx.x * 64;
    const int n    = pos0 >> 12;
    const int hw0  = pos0 & 4095;
    const float* __restrict__ xbase = x + (size_t)n * (CDIM * HWSZ) + hw0;

    // ---- A staging: x fp32 -> fp16 {xh, xh/64, xl*64}, [16 kc][2 kh][64 pos][16B]
    {
        const int i = t & 63;          // position (coalesced)
        const int g = t >> 6;          // channel group 0..15 (16 ch each)
        float x2p = 0.f;
        #pragma unroll
        for (int j = 0; j < 2; ++j) {
            const int c0 = g * 16 + j * 8;
            u16x8 hv, lv, hv64;
            #pragma unroll
            for (int q = 0; q < 8; ++q) {
                float vv = xbase[(size_t)(c0 + q) * HWSZ + i];
                x2p = fmaf(vv, vv, x2p);
                _Float16 hh = (_Float16)vv;
                hv[q]   = __builtin_bit_cast(unsigned short, hh);
                lv[q]   = f2h((vv - (float)hh) * 64.0f);
                hv64[q] = f2h((float)hh * 0.015625f);
            }
            const int byte = g * 2048 + j * 1024 + i * 16;   // kc=g, kh=j
            *reinterpret_cast<u16x8*>(lds + byte)         = hv;    // xh
            *reinterpret_cast<u16x8*>(lds + byte + 32768) = hv64;  // xh/64
            *reinterpret_cast<u16x8*>(lds + byte + 65536) = lv;    // xl*64
        }
        ((float*)(lds + X2P))[g * 64 + i] = x2p;
    }
    __syncthreads();

    // x2 totals
    if (t < 64) {
        const float* p = (const float*)(lds + X2P);
        float s = 0.f;
        #pragma unroll
        for (int g = 0; g < 16; ++g) s += p[g * 64 + t];
        ((float*)(lds + X2T))[t] = s;
    }
    __syncthreads();

    f32x16 acc00 = {}, acc01 = {}, acc10 = {}, acc11 = {};

    const int aoff = hi * 1024 + col32 * 16;   // + ra*512 ; + region*32768 + kc*2048
    const unsigned char* __restrict__ bl =
        ebuf + (size_t)((widx * 64 + col32) * 32 + hi * 16);   // + kq*32768 + cb*1024

    auto bload = [&](int kq, int cb) {
        return *reinterpret_cast<const f16x8*>(bl + (size_t)kq * 32768 + cb * 1024);
    };
    auto aload = [&](int kq, int ra) {
        // A region = kq>>4 (seg), chunk = kq&15
        return *reinterpret_cast<const f16x8*>(
            lds + (kq >> 4) * 32768 + (kq & 15) * 2048 + aoff + ra * 512);
    };

    // ---- main loop: 48 steps, unroll 2, B reg-double-buffered, no barriers
    f16x8 b0 = bload(0, 0), b1 = bload(0, 1);
    for (int kq = 0; kq < 48; kq += 2) {
        f16x8 b0n = bload(kq + 1, 0), b1n = bload(kq + 1, 1);
        f16x8 a0 = aload(kq, 0), a1 = aload(kq, 1);
        __builtin_amdgcn_s_setprio(1);
        acc00 = __builtin_amdgcn_mfma_f32_32x32x16_f16(a0, b0, acc00, 0, 0, 0);
        acc01 = __builtin_amdgcn_mfma_f32_32x32x16_f16(a0, b1, acc01, 0, 0, 0);
        acc10 = __builtin_amdgcn_mfma_f32_32x32x16_f16(a1, b0, acc10, 0, 0, 0);
        acc11 = __builtin_amdgcn_mfma_f32_32x32x16_f16(a1, b1, acc11, 0, 0, 0);
        __builtin_amdgcn_s_setprio(0);

        b0 = bload(kq + 2, 0); b1 = bload(kq + 2, 1);   // kq=46 -> harmless over-read
        f16x8 a0n = aload(kq + 1, 0), a1n = aload(kq + 1, 1);
        __builtin_amdgcn_s_setprio(1);
        acc00 = __builtin_amdgcn_mfma_f32_32x32x16_f16(a0n, b0n, acc00, 0, 0, 0);
        acc01 = __builtin_amdgcn_mfma_f32_32x32x16_f16(a0n, b1n, acc01, 0, 0, 0);
        acc10 = __builtin_amdgcn_mfma_f32_32x32x16_f16(a1n, b0n, acc10, 0, 0, 0);
        acc11 = __builtin_amdgcn_mfma_f32_32x32x16_f16(a1n, b1n, acc11, 0, 0, 0);
        __builtin_amdgcn_s_setprio(0);
    }

    // ---- epilogue: scores, in-wave argmin, cross-wave merge
    const float* x2t = (const float*)(lds + X2T);
    const float e2v0 = e2buf[widx * 64 + col32];
    const float e2v1 = e2buf[widx * 64 + 32 + col32];

    float* mv = (float*)(lds + MVOFF);
    int*   mi = (int*)(lds + MIOFF);

    #pragma unroll
    for (int ra = 0; ra < 2; ++ra) {
        #pragma unroll
        for (int reg = 0; reg < 16; ++reg) {
            const int pos = ra * 32 + (reg & 3) + 8 * (reg >> 2) + 4 * hi;
            const float x2 = x2t[pos];
            const float d0 = (ra == 0) ? acc00[reg] : acc10[reg];
            const float d1 = (ra == 0) ? acc01[reg] : acc11[reg];
            float bv_ = (x2 - 2.0f * d0) + e2v0;
            int   bi_ = widx * 64 + col32;
            const float s1 = (x2 - 2.0f * d1) + e2v1;
            const int   c1 = widx * 64 + 32 + col32;
            if (s1 < bv_) { bv_ = s1; bi_ = c1; }
            // shuffle-merge over the 32 code columns (stays within 32-lane half)
            #pragma unroll
            for (int m = 1; m < 32; m <<= 1) {
                float ov = __shfl_xor(bv_, m, 64);
                int   oi = __shfl_xor(bi_, m, 64);
                if (ov < bv_ || (ov == bv_ && oi < bi_)) { bv_ = ov; bi_ = oi; }
            }
            if (col32 == 0) {
                mv[widx * 64 + pos] = bv_;
                mi[widx * 64 + pos] = bi_;
            }
        }
    }

    __syncthreads();
    if (t < 64) {
        float bv_ = mv[t];
        int   bi_ = mi[t];
        #pragma unroll
        for (int w = 1; w < 16; ++w) {
            const float ov = mv[w * 64 + t];
            const int   oi = mi[w * 64 + t];
            if (ov < bv_ || (ov == bv_ && oi < bi_)) { bv_ = ov; bi_ = oi; }
        }
        idx_out[pos0 + t] = (float)bi_;
        // diff partial = sum of min distances
        float d = bv_;
        #pragma unroll
        for (int m = 1; m < 64; m <<= 1) d += __shfl_xor(d, m, 64);
        if (t == 0) atomicAdd(out + DIFF_OFF, d * (1.0f / 33554432.0f));
    }
}

// ---------------------------------------------------------------------------
// gather: quantize = embed[idx] (NCHW). Diff already done in stage1.
// ---------------------------------------------------------------------------
__global__ __launch_bounds__(256) void vq_gather_kernel(const float* __restrict__ embed,
                                                        float* __restrict__ out) {
    const int tid = threadIdx.x;
    const int p = blockIdx.x * 256 + tid;
    const int n = p >> 12;
    const int hw = p & 4095;
    const int idx = (int)out[IDX_OFF + p];
    const float4* __restrict__ erow4 = reinterpret_cast<const float4*>(embed + (size_t)idx * CDIM);
    float* __restrict__ op = out + (size_t)n * (CDIM * HWSZ) + hw;

    #pragma unroll 8
    for (int c4 = 0; c4 < 64; ++c4) {
        const float4 e = erow4[c4];
        op[(size_t)(c4 * 4 + 0) * HWSZ] = e.x;
        op[(size_t)(c4 * 4 + 1) * HWSZ] = e.y;
        op[(size_t)(c4 * 4 + 2) * HWSZ] = e.z;
        op[(size_t)(c4 * 4 + 3) * HWSZ] = e.w;
    }
}

extern "C" void kernel_launch(void* const* d_in, const int* in_sizes, int n_in,
                              void* d_out, int out_size, void* d_ws, size_t ws_size,
                              hipStream_t stream) {
    const float* x = (const float*)d_in[0];
    const float* embed = (const float*)d_in[1];
    float* out = (float*)d_out;

    vq_prep_embed<<<KCODES, 64, 0, stream>>>(embed, out);
    vq_stage1<<<NPOS / 64, 1024, 0, stream>>>(x, out);
    vq_gather_kernel<<<NPOS / 256, 256, 0, stream>>>(embed, out);
}